// Round 5
// baseline (155.013 us; speedup 1.0000x reference)
//
#include <hip/hip_runtime.h>
#include <cstdint>

typedef _Float16 f16;
typedef _Float16 f16x2 __attribute__((ext_vector_type(2)));
typedef _Float16 f16x4 __attribute__((ext_vector_type(4)));
typedef _Float16 f16x8 __attribute__((ext_vector_type(8)));
typedef float f32x4 __attribute__((ext_vector_type(4)));

// wave-local LDS sync: HGCN reduction state is per-wave (64 lanes, lockstep)
#define WSYNC() asm volatile("s_waitcnt lgkmcnt(0)" ::: "memory")

#define BATCH 16384
#define NAG   32
#define OBS   96
#define SDIM  1024
#define NE    64
#define HIDN  256
#define NH    1024

// k_front grid layout
#define NB_CONV 512      // A'' frag-pack of states (128 mt x 4 ktg)
#define NB_PW   256      // W1 -> B'' frag-pack
#define NB_SM   101      // W2t, hcw2, b1cat
#define NB_FRONT (NB_CONV + NB_PW + NB_SM)

// ======================= K_FRONT: frag-order packs =======================
// A'' chunk id = ((mt*16+kt)*8 + i8)*2 + ks ; chunk = 64 lanes x 16B
//   element: row = mt*128 + i8*16 + (l&15), k = kt*64 + ks*32 + (l>>4)*8 + e
// B'' chunk id = ((nt*16+kt)*8 + j8)*2 + ks ; same element formula over N
__global__ __launch_bounds__(256) void k_front(
    const float* __restrict__ states,
    const float* __restrict__ w1a, const float* __restrict__ w1b,
    const float* __restrict__ w1c, const float* __restrict__ w1d,
    const float* __restrict__ b1a, const float* __restrict__ b1b,
    const float* __restrict__ b1c, const float* __restrict__ b1d,
    const float* __restrict__ w2a, const float* __restrict__ w2b,
    const float* __restrict__ w2c, const float* __restrict__ w2d,
    f16* __restrict__ App, f16* __restrict__ Bpp, float* __restrict__ b1cat,
    f16* __restrict__ W2t, f16* __restrict__ hcw2) {
    __shared__ __align__(16) char arena[34816];
    const int tid = threadIdx.x;
    const int w = tid >> 6, l = tid & 63;
    int bid = blockIdx.x;

    if (bid < NB_CONV) {                  // states fp32 -> A'' frag order
        float* tile = (float*)arena;      // [128][68]
        const int mt = bid >> 2, ktg = bid & 3;
        const int row = tid >> 1, cb = (tid & 1) * 32;
        for (int kq = 0; kq < 4; kq++) {
            const int kt = ktg * 4 + kq;
            const float* src = states + (size_t)(mt * 128 + row) * 1024 + kt * 64 + cb;
            #pragma unroll
            for (int q = 0; q < 8; q++)
                *(float4*)&tile[row * 68 + cb + q * 4] = *(const float4*)(src + q * 4);
            __syncthreads();
            f16* dst = App + (size_t)(mt * 16 + kt) * 8192;   // 16 chunks x 512 f16
            #pragma unroll
            for (int cc = 0; cc < 4; cc++) {
                const int c = w * 4 + cc;        // chunk 0..15
                const int i8 = c >> 1, ks = c & 1;
                const float* tr = &tile[(i8 * 16 + (l & 15)) * 68 + ks * 32 + (l >> 4) * 8];
                float4 u0 = *(const float4*)tr;
                float4 u1 = *(const float4*)(tr + 4);
                f16x8 h = { (f16)u0.x, (f16)u0.y, (f16)u0.z, (f16)u0.w,
                            (f16)u1.x, (f16)u1.y, (f16)u1.z, (f16)u1.w };
                *(f16x8*)(dst + c * 512 + l * 8) = h;
            }
            __syncthreads();
        }
        return;
    }
    bid -= NB_CONV;
    if (bid < NB_PW) {                    // W1 -> B'' frag order via LDS transpose
        float* tile = (float*)arena;      // [64][65]
        const int mlp = bid >> 6, k64 = (bid >> 2) & 15, c64 = bid & 3;
        const float* src = (mlp == 0) ? w1a : (mlp == 1) ? w1b : (mlp == 2) ? w1c : w1d;
        for (int i = tid; i < 4096; i += 256) {
            int kk = i >> 6, cc = i & 63;
            tile[kk * 65 + cc] = src[(size_t)(k64 * 64 + kk) * 256 + c64 * 64 + cc];
        }
        __syncthreads();
        const int nt = mlp * 2 + (c64 >> 1);
        const int j8 = (c64 & 1) * 4 + w;          // wave w handles jj = w
        const int col = w * 16 + (l & 15);         // col within 64-col tile
        #pragma unroll
        for (int ks = 0; ks < 2; ks++) {
            const int kk0 = ks * 32 + (l >> 4) * 8;
            f16x8 h;
            #pragma unroll
            for (int e = 0; e < 8; e++) h[e] = (f16)tile[(kk0 + e) * 65 + col];
            *(f16x8*)(Bpp + ((size_t)((nt * 16 + k64) * 8 + j8) * 2 + ks) * 512 + l * 8) = h;
        }
        return;
    }
    bid -= NB_PW;
    {                                     // W2t, hcw2, b1cat
        int i = bid * 256 + tid;
        if (i < 24576) {
            int mp = i >> 13, rem = i & 8191, oo = rem >> 8, kk = rem & 255;
            const float* src = (mp == 0) ? w2a : (mp == 1) ? w2b : w2c;
            W2t[i] = (f16)src[kk * 32 + oo];
        } else if (i < 24832) {
            int k = i - 24576;
            hcw2[k] = (f16)w2d[k];
        } else if (i < 25856) {
            int n = i - 24832;
            int mlp = n >> 8, c = n & 255;
            const float* bsrc = (mlp == 0) ? b1a : (mlp == 1) ? b1b : (mlp == 2) ? b1c : b1d;
            b1cat[n] = bsrc[c];
        }
    }
}

// ======================= K_GEMM: barrier-free register GEMM + fused layer-2 =======================
__global__ __launch_bounds__(256) void k_gemm(
    const f16* __restrict__ App, const f16* __restrict__ Bpp,
    const float* __restrict__ b1cat, const f16* __restrict__ W2t,
    const f16* __restrict__ hcw2, float* __restrict__ Pp) {
    __shared__ __align__(16) f16 Ts[128 * 132];   // relu'd tile for layer-2 pass

    const int tid = threadIdx.x;
    const int w = tid >> 6, l = tid & 63;
    const int lm = l & 15, lk = l >> 4;
    // same-mt blocks grouped per XCD so the A'' tile (256KB) is L2-shared
    const int p = blockIdx.x;
    const int xcd = p & 7, slot = p >> 3;
    const int mt = xcd * 16 + (slot >> 3);
    const int nt = slot & 7;
    const int m0 = mt * 128, n0 = nt * 128;
    const int wm = w >> 1, wn = w & 1;

    f32x4 acc[4][4];
    #pragma unroll
    for (int i = 0; i < 4; i++)
        #pragma unroll
        for (int j = 0; j < 4; j++) acc[i][j] = (f32x4){0.f, 0.f, 0.f, 0.f};

    const f16* Ab = App + ((size_t)mt * 16 * 16 + wm * 8) * 512 + l * 8;
    const f16* Bb = Bpp + ((size_t)nt * 16 * 16 + wn * 8) * 512 + l * 8;

    #pragma unroll 4
    for (int kt = 0; kt < 16; kt++) {
        const f16* Ak = Ab + (size_t)kt * 8192;
        const f16* Bk = Bb + (size_t)kt * 8192;
        f16x8 af[4][2], bf[4][2];
        #pragma unroll
        for (int i = 0; i < 4; i++)
            #pragma unroll
            for (int ks = 0; ks < 2; ks++) {
                af[i][ks] = *(const f16x8*)(Ak + (i * 2 + ks) * 512);
                bf[i][ks] = *(const f16x8*)(Bk + (i * 2 + ks) * 512);
            }
        #pragma unroll
        for (int ks = 0; ks < 2; ks++)
            #pragma unroll
            for (int i = 0; i < 4; i++)
                #pragma unroll
                for (int j = 0; j < 4; j++)
                    acc[i][j] = __builtin_amdgcn_mfma_f32_16x16x32_f16(af[i][ks], bf[j][ks], acc[i][j], 0, 0, 0);
    }

    // bias + relu -> Ts (f16), C-layout scatter
    float bj[4];
    #pragma unroll
    for (int j = 0; j < 4; j++) bj[j] = b1cat[n0 + wn * 64 + j * 16 + lm];
    #pragma unroll
    for (int i = 0; i < 4; i++)
        #pragma unroll
        for (int r = 0; r < 4; r++) {
            int row = wm * 64 + i * 16 + lk * 4 + r;
            #pragma unroll
            for (int j = 0; j < 4; j++) {
                int col = wn * 64 + j * 16 + lm;
                float v = acc[i][j][r] + bj[j];
                Ts[row * 132 + col] = (f16)(v > 0.f ? v : 0.f);
            }
        }
    __syncthreads();

    // fused layer-2 K-half partial: this block's 128 cols = half of MLP (nt>>1)'s K=256
    const int mlp = nt >> 1, kh = nt & 1;
    const int rbase = w * 32;
    if (mlp < 3) {
        const f16* wb = W2t + mlp * 8192 + kh * 128;   // W2t[o][k] rows, k-slice
        f32x4 acc2[2][2];
        acc2[0][0] = (f32x4){0,0,0,0}; acc2[0][1] = (f32x4){0,0,0,0};
        acc2[1][0] = (f32x4){0,0,0,0}; acc2[1][1] = (f32x4){0,0,0,0};
        #pragma unroll
        for (int ks = 0; ks < 4; ks++) {
            f16x8 b0 = *(const f16x8*)&wb[lm * 256 + ks * 32 + lk * 8];
            f16x8 b1 = *(const f16x8*)&wb[(16 + lm) * 256 + ks * 32 + lk * 8];
            #pragma unroll
            for (int i2 = 0; i2 < 2; i2++) {
                f16x8 a = *(const f16x8*)&Ts[(rbase + i2 * 16 + lm) * 132 + ks * 32 + lk * 8];
                acc2[i2][0] = __builtin_amdgcn_mfma_f32_16x16x32_f16(a, b0, acc2[i2][0], 0, 0, 0);
                acc2[i2][1] = __builtin_amdgcn_mfma_f32_16x16x32_f16(a, b1, acc2[i2][1], 0, 0, 0);
            }
        }
        #pragma unroll
        for (int i2 = 0; i2 < 2; i2++)
            #pragma unroll
            for (int j2 = 0; j2 < 2; j2++)
                #pragma unroll
                for (int r = 0; r < 4; r++)
                    Pp[((size_t)kh * BATCH + m0 + rbase + i2 * 16 + lk * 4 + r) * 104
                       + mlp * 32 + j2 * 16 + lm] = acc2[i2][j2][r];
    } else {
        const f16* hc = hcw2 + kh * 128;
        f32x4 acc2[2];
        acc2[0] = (f32x4){0,0,0,0}; acc2[1] = (f32x4){0,0,0,0};
        #pragma unroll
        for (int ks = 0; ks < 4; ks++) {
            f16x8 bz = (f16x8){0,0,0,0,0,0,0,0};
            if (lm == 0) bz = *(const f16x8*)&hc[ks * 32 + lk * 8];
            #pragma unroll
            for (int i2 = 0; i2 < 2; i2++) {
                f16x8 a = *(const f16x8*)&Ts[(rbase + i2 * 16 + lm) * 132 + ks * 32 + lk * 8];
                acc2[i2] = __builtin_amdgcn_mfma_f32_16x16x32_f16(a, bz, acc2[i2], 0, 0, 0);
            }
        }
        if (lm == 0)
            #pragma unroll
            for (int i2 = 0; i2 < 2; i2++)
                #pragma unroll
                for (int r = 0; r < 4; r++)
                    Pp[((size_t)kh * BATCH + m0 + rbase + i2 * 16 + lk * 4 + r) * 104 + 96]
                        = acc2[i2][r];
    }
}

// ======================= K_HGCN_EP: HGCN + fused mix epilogue (f32 aux) =======================
__global__ __launch_bounds__(256) void k_hgcn_ep(
    const float* __restrict__ agent_qs, const float* __restrict__ indiv_us,
    const float* __restrict__ edge_W, const float* __restrict__ edge_b,
    const float* __restrict__ wline1, const float* __restrict__ wline2,
    const float* __restrict__ Pp,
    const float* __restrict__ hw1_b2, const float* __restrict__ hc1_b2,
    const float* __restrict__ hw_b2, const float* __restrict__ hc_b2,
    float* __restrict__ out) {
    // arena: eWs 13312 | swa 512 | Hs(f16) 16896 | sv 1024 | stt 512 | sdis 1024 | sbinv 1024 = 34304
    __shared__ __align__(16) char arena[34304];
    f16*   eWs   = (f16*)arena;
    float* swa   = (float*)(arena + 13312);
    f16*   HsB   = (f16*)(arena + 13824);
    float* svB   = (float*)(arena + 30720);
    float* sttB  = (float*)(arena + 31744);
    float* sdisB = (float*)(arena + 32256);
    float* sbinvB= (float*)(arena + 33280);

    const int tid = threadIdx.x;
    const int w = tid >> 6, l = tid & 63;
    const int b = blockIdx.x * 4 + w;
    f16*   Hw    = HsB + w * (32 * 66);
    float* sv    = svB + w * 64;
    float* stt   = sttB + w * 32;
    float* sdis  = sdisB + w * 64;
    float* sbinv = sbinvB + w * 64;

    const int nn = l & 31, half = l >> 5;

    // T14: issue epilogue loads early (lanes 0-31), consume after y2
    float pa0 = 0.f, pa1 = 0.f, pc0 = 0.f, pc1 = 0.f, pw0 = 0.f, pw1 = 0.f;
    float p96a = 0.f, p96b = 0.f, bw1 = 0.f, bc1 = 0.f, bww = 0.f, bhc = 0.f;
    if (half == 0) {
        const float* p0 = Pp + (size_t)b * 104;
        const float* p1 = Pp + (size_t)(BATCH + b) * 104;
        pa0 = p0[nn];      pa1 = p1[nn];
        pc0 = p0[32 + nn]; pc1 = p1[32 + nn];
        pw0 = p0[64 + nn]; pw1 = p1[64 + nn];
        p96a = p0[96];     p96b = p1[96];
        bw1 = hw1_b2[nn];  bc1 = hc1_b2[nn];
        bww = hw_b2[nn];   bhc = hc_b2[0];
    }
    float q = agent_qs[(size_t)b * 32 + nn];

    // inline edge_W transpose: edge_W[k][n] -> eWs[n][k]
    for (int i = tid; i < 6144; i += 256) {
        int k = i >> 6, n = i & 63;
        eWs[n * 104 + k] = (f16)edge_W[i];
    }
    if (tid < 64) swa[tid] = fabsf(wline1[tid]);
    else if (tid < 128) swa[tid] = fabsf(wline2[tid - 64]);
    __syncthreads();   // the only block-wide barrier (eWs/swa are cross-wave)

    const int lm = l & 15, lk = l >> 4;
    const float* ub = indiv_us + (size_t)b * (NAG * OBS);

    // H = relu(u @ W^T + b)
    #pragma unroll
    for (int mt = 0; mt < 2; mt++) {
        f16x8 af[3];
        #pragma unroll
        for (int ks = 0; ks < 3; ks++) {
            const float* up = ub + (mt * 16 + lm) * 96 + ks * 32 + lk * 8;
            float4 v0 = *(const float4*)up;
            float4 v1 = *(const float4*)(up + 4);
            af[ks] = (f16x8){ (f16)v0.x, (f16)v0.y, (f16)v0.z, (f16)v0.w,
                              (f16)v1.x, (f16)v1.y, (f16)v1.z, (f16)v1.w };
        }
        #pragma unroll
        for (int nt = 0; nt < 4; nt++) {
            f32x4 acc = {0.f, 0.f, 0.f, 0.f};
            #pragma unroll
            for (int ks = 0; ks < 3; ks++) {
                f16x8 bb = *(const f16x8*)&eWs[(nt * 16 + lm) * 104 + ks * 32 + lk * 8];
                acc = __builtin_amdgcn_mfma_f32_16x16x32_f16(af[ks], bb, acc, 0, 0, 0);
            }
            int col = nt * 16 + lm;
            float bias = edge_b[col];
            #pragma unroll
            for (int r = 0; r < 4; r++) {
                int row = mt * 16 + lk * 4 + r;
                float hv = acc[r] + bias;
                Hw[row * 66 + col] = (f16)(hv > 0.f ? hv : 0.f);
            }
        }
    }
    WSYNC();

    float bsum = 0.f;
    #pragma unroll
    for (int n = 0; n < 32; n++) bsum += (float)Hw[n * 66 + l];
    sbinv[l] = bsum > 0.f ? 1.f / bsum : 0.f;

    float dd = 0.f;
    #pragma unroll 8
    for (int e2 = 0; e2 < 32; e2++) {
        f16x2 h2 = *(const f16x2*)&Hw[nn * 66 + e2 * 2];
        dd += (float)h2.x * swa[half * 64 + e2 * 2] + (float)h2.y * swa[half * 64 + e2 * 2 + 1];
    }
    float dis = dd > 0.f ? rsqrtf(dd) : 0.f;
    sdis[l] = dis;
    if (half == 0) stt[nn] = dis * q;
    WSYNC();

    float s1 = 0.f;
    #pragma unroll
    for (int n = 0; n < 32; n++) s1 += (float)Hw[n * 66 + l] * stt[n];
    sv[l] = s1 * swa[l] * sbinv[l];
    WSYNC();

    float y1 = 0.f;
    #pragma unroll 8
    for (int e2 = 0; e2 < 32; e2++) {
        f16x2 h2 = *(const f16x2*)&Hw[nn * 66 + e2 * 2];
        y1 += (float)h2.x * sv[e2 * 2] + (float)h2.y * sv[e2 * 2 + 1];
    }
    float x2 = sdis[nn] * y1;
    if (half == 0) stt[nn] = sdis[32 + nn] * x2;
    WSYNC();

    float s2 = 0.f;
    #pragma unroll
    for (int n = 0; n < 32; n++) s2 += (float)Hw[n * 66 + l] * stt[n];
    sv[l] = s2 * swa[64 + l] * sbinv[l];
    WSYNC();

    float y2 = 0.f;
    #pragma unroll 8
    for (int e2 = 0; e2 < 32; e2++) {
        f16x2 h2 = *(const f16x2*)&Hw[nn * 66 + e2 * 2];
        y2 += (float)h2.x * sv[e2 * 2] + (float)h2.y * sv[e2 * 2 + 1];
    }

    // ---- fused mix epilogue (lanes 0-31 of each wave) ----
    float qsv = sdis[32 + nn] * y2;
    float w1v = fabsf(pa0 + pa1 + bw1);
    float c1v = pc0 + pc1 + bc1;
    float wwv = fabsf(pw0 + pw1 + bww);
    float z = qsv * w1v + c1v;
    float qt = z > 0.f ? z : expm1f(z);
    float val = (half == 0) ? qt * wwv : 0.f;
    val += __shfl_xor(val, 1, 32);
    val += __shfl_xor(val, 2, 32);
    val += __shfl_xor(val, 4, 32);
    val += __shfl_xor(val, 8, 32);
    val += __shfl_xor(val, 16, 32);
    if (l == 0) out[b] = val + p96a + p96b + bhc;
}

// ======================= launch =======================
extern "C" void kernel_launch(void* const* d_in, const int* in_sizes, int n_in,
                              void* d_out, int out_size, void* d_ws, size_t ws_size,
                              hipStream_t stream) {
    const float* agent_qs = (const float*)d_in[0];
    const float* states   = (const float*)d_in[1];
    const float* indiv_us = (const float*)d_in[2];
    const float* edge_W   = (const float*)d_in[3];
    const float* edge_b   = (const float*)d_in[4];
    const float* wline1   = (const float*)d_in[5];
    const float* wline2   = (const float*)d_in[6];
    const float* hw1_w1 = (const float*)d_in[7];
    const float* hw1_b1 = (const float*)d_in[8];
    const float* hw1_w2 = (const float*)d_in[9];
    const float* hw1_b2 = (const float*)d_in[10];
    const float* hc1_w1 = (const float*)d_in[11];
    const float* hc1_b1 = (const float*)d_in[12];
    const float* hc1_w2 = (const float*)d_in[13];
    const float* hc1_b2 = (const float*)d_in[14];
    const float* hw_w1  = (const float*)d_in[15];
    const float* hw_b1  = (const float*)d_in[16];
    const float* hw_w2  = (const float*)d_in[17];
    const float* hw_b2  = (const float*)d_in[18];
    const float* hc_w1  = (const float*)d_in[19];
    const float* hc_b1  = (const float*)d_in[20];
    const float* hc_w2  = (const float*)d_in[21];
    const float* hc_b2  = (const float*)d_in[22];

    char* ws = (char*)d_ws;
    size_t o_App  = 0;                                       // 33,554,432
    size_t o_Bpp  = o_App + (size_t)BATCH * SDIM * 2;        // 2,097,152
    size_t o_b1   = o_Bpp + (size_t)NH * SDIM * 2;           // 4096
    size_t o_W2t  = o_b1 + 4096;                             // 49,152
    size_t o_hcw2 = o_W2t + 49152;                           // 512
    size_t o_Pp   = o_hcw2 + 512;                            // 2*16384*104*4

    f16*   App    = (f16*)(ws + o_App);
    f16*   Bpp    = (f16*)(ws + o_Bpp);
    float* b1cat  = (float*)(ws + o_b1);
    f16*   W2t    = (f16*)(ws + o_W2t);
    f16*   hcw2   = (f16*)(ws + o_hcw2);
    float* Pp     = (float*)(ws + o_Pp);

    k_front<<<NB_FRONT, 256, 0, stream>>>(
        states,
        hw1_w1, hc1_w1, hw_w1, hc_w1, hw1_b1, hc1_b1, hw_b1, hc_b1,
        hw1_w2, hc1_w2, hw_w2, hc_w2,
        App, Bpp, b1cat, W2t, hcw2);
    k_gemm<<<1024, 256, 0, stream>>>(App, Bpp, b1cat, W2t, hcw2, Pp);
    k_hgcn_ep<<<BATCH / 4, 256, 0, stream>>>(
        agent_qs, indiv_us, edge_W, edge_b, wline1, wline2, Pp,
        hw1_b2, hc1_b2, hw_b2, hc_b2, (float*)d_out);
}

// Round 6
// 124.087 us; speedup vs baseline: 1.2492x; 1.2492x over previous
//
#include <hip/hip_runtime.h>
#include <cstdint>

typedef _Float16 f16;
typedef _Float16 f16x2 __attribute__((ext_vector_type(2)));
typedef _Float16 f16x4 __attribute__((ext_vector_type(4)));
typedef _Float16 f16x8 __attribute__((ext_vector_type(8)));
typedef float f32x4 __attribute__((ext_vector_type(4)));

#define AS1U const __attribute__((address_space(1))) unsigned int
#define AS3U __attribute__((address_space(3))) unsigned int

__device__ __forceinline__ void gload_lds16(const void* g, void* l) {
    __builtin_amdgcn_global_load_lds((AS1U*)g, (AS3U*)l, 16, 0, 0);
}

// wave-local LDS sync: HGCN reduction state is per-wave (64 lanes, lockstep)
#define WSYNC() asm volatile("s_waitcnt lgkmcnt(0)" ::: "memory")

#define BATCH 16384
#define NAG   32
#define OBS   96
#define SDIM  1024
#define NE    64
#define HIDN  256
#define NH    1024

// k_front grid layout (conv + packs)
#define NB_ST 1024
#define NB_PW 256
#define NB_SM 101
#define NB_FRONT (NB_ST + NB_PW + NB_SM)

// ======================= K_FRONT: states conv + weight packs =======================
__global__ __launch_bounds__(256) void k_front(
    const float* __restrict__ states,
    const float* __restrict__ w1a, const float* __restrict__ w1b,
    const float* __restrict__ w1c, const float* __restrict__ w1d,
    const float* __restrict__ b1a, const float* __restrict__ b1b,
    const float* __restrict__ b1c, const float* __restrict__ b1d,
    const float* __restrict__ w2a, const float* __restrict__ w2b,
    const float* __restrict__ w2c, const float* __restrict__ w2d,
    f16* __restrict__ states16, f16* __restrict__ W1t, float* __restrict__ b1cat,
    f16* __restrict__ W2t, f16* __restrict__ hcw2) {
    __shared__ float tile[64 * 65];
    const int tid = threadIdx.x;
    int bid = blockIdx.x;

    if (bid < NB_ST) {                    // states fp32 -> fp16
        int i = bid * 256 + tid;
        const int n4 = BATCH * SDIM / 4;
        const int stride = NB_ST * 256;
        for (; i < n4; i += stride) {
            float4 v = ((const float4*)states)[i];
            f16x4 h = { (f16)v.x, (f16)v.y, (f16)v.z, (f16)v.w };
            ((f16x4*)states16)[i] = h;
        }
        return;
    }
    bid -= NB_ST;
    if (bid < NB_PW) {                    // W1 pack via LDS transpose (coalesced both sides)
        int mlp = bid >> 6, rem = bid & 63, kt = rem >> 2, ct = rem & 3;
        const float* src = (mlp == 0) ? w1a : (mlp == 1) ? w1b : (mlp == 2) ? w1c : w1d;
        int k0 = kt * 64, c0 = ct * 64;
        for (int i = tid; i < 4096; i += 256) {
            int kk = i >> 6, cc = i & 63;
            tile[kk * 65 + cc] = src[(size_t)(k0 + kk) * 256 + c0 + cc];
        }
        __syncthreads();
        for (int i = tid; i < 4096; i += 256) {
            int cc = i >> 6, kk = i & 63;
            W1t[(size_t)(mlp * 256 + c0 + cc) * 1024 + k0 + kk] = (f16)tile[kk * 65 + cc];
        }
        return;
    }
    bid -= NB_PW;
    {                                     // W2t, hcw2, b1cat
        int i = bid * 256 + tid;
        if (i < 24576) {
            int mp = i >> 13, rem = i & 8191, oo = rem >> 8, kk = rem & 255;
            const float* src = (mp == 0) ? w2a : (mp == 1) ? w2b : w2c;
            W2t[i] = (f16)src[kk * 32 + oo];
        } else if (i < 24832) {
            int k = i - 24576;
            hcw2[k] = (f16)w2d[k];
        } else if (i < 25856) {
            int n = i - 24832;
            int mlp = n >> 8, c = n & 255;
            const float* bsrc = (mlp == 0) ? b1a : (mlp == 1) ? b1b : (mlp == 2) ? b1c : b1d;
            b1cat[n] = bsrc[c];
        }
    }
}

// ======================= K_GEMM: 256x256 dbuf one-barrier pipeline + fused layer-2 =======================
// minimum-2-phase recipe: STAGE(next) issued BEFORE compute(cur); single __syncthreads per kt
// (its implicit vmcnt(0) drain lands AFTER the MFMA phase, so load latency hides under compute).
__global__ __launch_bounds__(512) void k_gemm(
    const f16* __restrict__ A, const f16* __restrict__ B,
    const float* __restrict__ b1cat, const f16* __restrict__ W2t,
    const f16* __restrict__ hcw2, float* __restrict__ Pp) {
    __shared__ __align__(16) char smem[131072];
    f16* Asb = (f16*)smem;                  // [2][256][64]
    f16* Bsb = (f16*)(smem + 65536);        // [2][256][64]
    f16* Ts  = (f16*)smem;                  // [128][264] relu'd half-tile (after K-loop)

    const int tid = threadIdx.x;
    const int w = tid >> 6, l = tid & 63;
    const int lm = l & 15, lk = l >> 4;
    const int wm = w >> 2, wn = w & 3;      // 2M x 4N waves
    // XCD map: 4 same-mt blocks (nt fast) adjacent per XCD -> shared A panel in L2
    const int p = blockIdx.x;
    const int xcd = p & 7, s = p >> 3;
    const int mt = xcd * 8 + (s >> 2);      // 0..63
    const int nt = s & 3;                   // 0..3 == mlp
    const int m0 = mt * 256, n0 = nt * 256;
    const int c0 = w * 4;                   // first staging chunk (of 32 per operand)
    const int srow = l >> 3, scol = (l & 7) * 8;

    f32x4 acc[8][4];
    #pragma unroll
    for (int i = 0; i < 8; i++)
        #pragma unroll
        for (int j = 0; j < 4; j++) acc[i][j] = (f32x4){0.f, 0.f, 0.f, 0.f};

    // prologue: stage kt=0 into buf0
    #pragma unroll
    for (int i = 0; i < 4; i++) {
        int cc = c0 + i;
        gload_lds16(&A[(size_t)(m0 + cc * 8 + srow) * 1024 + scol], &Asb[cc * 512]);
        gload_lds16(&B[(size_t)(n0 + cc * 8 + srow) * 1024 + scol], &Bsb[cc * 512]);
    }
    __syncthreads();

    int cur = 0;
    for (int kt = 0; kt < 16; kt++) {
        if (kt < 15) {                       // issue next-tile loads first (uniform branch)
            f16* Ad = Asb + (cur ^ 1) * 16384;
            f16* Bd = Bsb + (cur ^ 1) * 16384;
            #pragma unroll
            for (int i = 0; i < 4; i++) {
                int cc = c0 + i;
                gload_lds16(&A[(size_t)(m0 + cc * 8 + srow) * 1024 + (kt + 1) * 64 + scol], &Ad[cc * 512]);
                gload_lds16(&B[(size_t)(n0 + cc * 8 + srow) * 1024 + (kt + 1) * 64 + scol], &Bd[cc * 512]);
            }
        }
        const f16* As_ = Asb + cur * 16384;
        const f16* Bs_ = Bsb + cur * 16384;
        #pragma unroll
        for (int ks = 0; ks < 2; ks++) {
            f16x8 af[8], bf[4];
            #pragma unroll
            for (int i = 0; i < 8; i++)
                af[i] = *(const f16x8*)&As_[(wm * 128 + i * 16 + lm) * 64 + ks * 32 + lk * 8];
            #pragma unroll
            for (int j = 0; j < 4; j++)
                bf[j] = *(const f16x8*)&Bs_[(wn * 64 + j * 16 + lm) * 64 + ks * 32 + lk * 8];
            #pragma unroll
            for (int i = 0; i < 8; i++)
                #pragma unroll
                for (int j = 0; j < 4; j++)
                    acc[i][j] = __builtin_amdgcn_mfma_f32_16x16x32_f16(af[i], bf[j], acc[i][j], 0, 0, 0);
        }
        __syncthreads();                     // readers done + next tile landed (vmcnt0 drain)
        cur ^= 1;
    }

    // ---- epilogue: bias+relu -> Ts, layer-2 per 128-row pass; block covers FULL mlp (K=256) ----
    float bj[4];
    #pragma unroll
    for (int j = 0; j < 4; j++) bj[j] = b1cat[n0 + wn * 64 + j * 16 + lm];
    const int mlp = nt;

    #pragma unroll
    for (int pass = 0; pass < 2; pass++) {
        if (wm == pass) {
            #pragma unroll
            for (int i = 0; i < 8; i++)
                #pragma unroll
                for (int r = 0; r < 4; r++) {
                    int rl = i * 16 + lk * 4 + r;
                    #pragma unroll
                    for (int j = 0; j < 4; j++) {
                        float v = acc[i][j][r] + bj[j];
                        Ts[rl * 264 + wn * 64 + j * 16 + lm] = (f16)(v > 0.f ? v : 0.f);
                    }
                }
        }
        __syncthreads();
        const int grow = m0 + pass * 128 + w * 16;
        if (mlp < 3) {
            const f16* wb = W2t + mlp * 8192;
            f32x4 acc2[2];
            acc2[0] = (f32x4){0, 0, 0, 0}; acc2[1] = (f32x4){0, 0, 0, 0};
            #pragma unroll
            for (int ks = 0; ks < 8; ks++) {
                f16x8 a  = *(const f16x8*)&Ts[(w * 16 + lm) * 264 + ks * 32 + lk * 8];
                f16x8 b0 = *(const f16x8*)&wb[lm * 256 + ks * 32 + lk * 8];
                f16x8 b1 = *(const f16x8*)&wb[(16 + lm) * 256 + ks * 32 + lk * 8];
                acc2[0] = __builtin_amdgcn_mfma_f32_16x16x32_f16(a, b0, acc2[0], 0, 0, 0);
                acc2[1] = __builtin_amdgcn_mfma_f32_16x16x32_f16(a, b1, acc2[1], 0, 0, 0);
            }
            #pragma unroll
            for (int j2 = 0; j2 < 2; j2++)
                #pragma unroll
                for (int r = 0; r < 4; r++)
                    Pp[(size_t)(grow + lk * 4 + r) * 104 + mlp * 32 + j2 * 16 + lm] = acc2[j2][r];
        } else {
            f32x4 acc2 = (f32x4){0, 0, 0, 0};
            #pragma unroll
            for (int ks = 0; ks < 8; ks++) {
                f16x8 a = *(const f16x8*)&Ts[(w * 16 + lm) * 264 + ks * 32 + lk * 8];
                f16x8 bz = (f16x8){0, 0, 0, 0, 0, 0, 0, 0};
                if (lm == 0) bz = *(const f16x8*)&hcw2[ks * 32 + lk * 8];
                acc2 = __builtin_amdgcn_mfma_f32_16x16x32_f16(a, bz, acc2, 0, 0, 0);
            }
            if (lm == 0)
                #pragma unroll
                for (int r = 0; r < 4; r++)
                    Pp[(size_t)(grow + lk * 4 + r) * 104 + 96] = acc2[r];
        }
        if (pass == 0) __syncthreads();      // protect Ts before pass-1 overwrite
    }
}

// ======================= K_HGCN_EP: HGCN + fused mix epilogue (f32 aux, single Pp) =======================
__global__ __launch_bounds__(256) void k_hgcn_ep(
    const float* __restrict__ agent_qs, const float* __restrict__ indiv_us,
    const float* __restrict__ edge_W, const float* __restrict__ edge_b,
    const float* __restrict__ wline1, const float* __restrict__ wline2,
    const float* __restrict__ Pp,
    const float* __restrict__ hw1_b2, const float* __restrict__ hc1_b2,
    const float* __restrict__ hw_b2, const float* __restrict__ hc_b2,
    float* __restrict__ out) {
    // arena: eWs 13312 | swa 512 | Hs(f16) 16896 | sv 1024 | stt 512 | sdis 1024 | sbinv 1024 = 34304
    __shared__ __align__(16) char arena[34304];
    f16*   eWs   = (f16*)arena;
    float* swa   = (float*)(arena + 13312);
    f16*   HsB   = (f16*)(arena + 13824);
    float* svB   = (float*)(arena + 30720);
    float* sttB  = (float*)(arena + 31744);
    float* sdisB = (float*)(arena + 32256);
    float* sbinvB= (float*)(arena + 33280);

    const int tid = threadIdx.x;
    const int w = tid >> 6, l = tid & 63;
    const int b = blockIdx.x * 4 + w;
    f16*   Hw    = HsB + w * (32 * 66);
    float* sv    = svB + w * 64;
    float* stt   = sttB + w * 32;
    float* sdis  = sdisB + w * 64;
    float* sbinv = sbinvB + w * 64;

    const int nn = l & 31, half = l >> 5;

    // T14: issue epilogue loads early (lanes 0-31), consume after y2
    float pa0 = 0.f, pc0 = 0.f, pw0 = 0.f;
    float p96a = 0.f, bw1 = 0.f, bc1 = 0.f, bww = 0.f, bhc = 0.f;
    if (half == 0) {
        const float* p0 = Pp + (size_t)b * 104;
        pa0 = p0[nn];
        pc0 = p0[32 + nn];
        pw0 = p0[64 + nn];
        p96a = p0[96];
        bw1 = hw1_b2[nn];  bc1 = hc1_b2[nn];
        bww = hw_b2[nn];   bhc = hc_b2[0];
    }
    float q = agent_qs[(size_t)b * 32 + nn];

    // inline edge_W transpose: edge_W[k][n] -> eWs[n][k]
    for (int i = tid; i < 6144; i += 256) {
        int k = i >> 6, n = i & 63;
        eWs[n * 104 + k] = (f16)edge_W[i];
    }
    if (tid < 64) swa[tid] = fabsf(wline1[tid]);
    else if (tid < 128) swa[tid] = fabsf(wline2[tid - 64]);
    __syncthreads();   // the only block-wide barrier (eWs/swa are cross-wave)

    const int lm = l & 15, lk = l >> 4;
    const float* ub = indiv_us + (size_t)b * (NAG * OBS);

    // H = relu(u @ W^T + b)
    #pragma unroll
    for (int mt = 0; mt < 2; mt++) {
        f16x8 af[3];
        #pragma unroll
        for (int ks = 0; ks < 3; ks++) {
            const float* up = ub + (mt * 16 + lm) * 96 + ks * 32 + lk * 8;
            float4 v0 = *(const float4*)up;
            float4 v1 = *(const float4*)(up + 4);
            af[ks] = (f16x8){ (f16)v0.x, (f16)v0.y, (f16)v0.z, (f16)v0.w,
                              (f16)v1.x, (f16)v1.y, (f16)v1.z, (f16)v1.w };
        }
        #pragma unroll
        for (int nt = 0; nt < 4; nt++) {
            f32x4 acc = {0.f, 0.f, 0.f, 0.f};
            #pragma unroll
            for (int ks = 0; ks < 3; ks++) {
                f16x8 bb = *(const f16x8*)&eWs[(nt * 16 + lm) * 104 + ks * 32 + lk * 8];
                acc = __builtin_amdgcn_mfma_f32_16x16x32_f16(af[ks], bb, acc, 0, 0, 0);
            }
            int col = nt * 16 + lm;
            float bias = edge_b[col];
            #pragma unroll
            for (int r = 0; r < 4; r++) {
                int row = mt * 16 + lk * 4 + r;
                float hv = acc[r] + bias;
                Hw[row * 66 + col] = (f16)(hv > 0.f ? hv : 0.f);
            }
        }
    }
    WSYNC();

    float bsum = 0.f;
    #pragma unroll
    for (int n = 0; n < 32; n++) bsum += (float)Hw[n * 66 + l];
    sbinv[l] = bsum > 0.f ? 1.f / bsum : 0.f;

    float dd = 0.f;
    #pragma unroll 8
    for (int e2 = 0; e2 < 32; e2++) {
        f16x2 h2 = *(const f16x2*)&Hw[nn * 66 + e2 * 2];
        dd += (float)h2.x * swa[half * 64 + e2 * 2] + (float)h2.y * swa[half * 64 + e2 * 2 + 1];
    }
    float dis = dd > 0.f ? rsqrtf(dd) : 0.f;
    sdis[l] = dis;
    if (half == 0) stt[nn] = dis * q;
    WSYNC();

    float s1 = 0.f;
    #pragma unroll
    for (int n = 0; n < 32; n++) s1 += (float)Hw[n * 66 + l] * stt[n];
    sv[l] = s1 * swa[l] * sbinv[l];
    WSYNC();

    float y1 = 0.f;
    #pragma unroll 8
    for (int e2 = 0; e2 < 32; e2++) {
        f16x2 h2 = *(const f16x2*)&Hw[nn * 66 + e2 * 2];
        y1 += (float)h2.x * sv[e2 * 2] + (float)h2.y * sv[e2 * 2 + 1];
    }
    float x2 = sdis[nn] * y1;
    if (half == 0) stt[nn] = sdis[32 + nn] * x2;
    WSYNC();

    float s2 = 0.f;
    #pragma unroll
    for (int n = 0; n < 32; n++) s2 += (float)Hw[n * 66 + l] * stt[n];
    sv[l] = s2 * swa[64 + l] * sbinv[l];
    WSYNC();

    float y2 = 0.f;
    #pragma unroll 8
    for (int e2 = 0; e2 < 32; e2++) {
        f16x2 h2 = *(const f16x2*)&Hw[nn * 66 + e2 * 2];
        y2 += (float)h2.x * sv[e2 * 2] + (float)h2.y * sv[e2 * 2 + 1];
    }

    // ---- fused mix epilogue (lanes 0-31 of each wave) ----
    float qsv = sdis[32 + nn] * y2;
    float w1v = fabsf(pa0 + bw1);
    float c1v = pc0 + bc1;
    float wwv = fabsf(pw0 + bww);
    float z = qsv * w1v + c1v;
    float qt = z > 0.f ? z : expm1f(z);
    float val = (half == 0) ? qt * wwv : 0.f;
    val += __shfl_xor(val, 1, 32);
    val += __shfl_xor(val, 2, 32);
    val += __shfl_xor(val, 4, 32);
    val += __shfl_xor(val, 8, 32);
    val += __shfl_xor(val, 16, 32);
    if (l == 0) out[b] = val + p96a + bhc;
}

// ======================= launch =======================
extern "C" void kernel_launch(void* const* d_in, const int* in_sizes, int n_in,
                              void* d_out, int out_size, void* d_ws, size_t ws_size,
                              hipStream_t stream) {
    const float* agent_qs = (const float*)d_in[0];
    const float* states   = (const float*)d_in[1];
    const float* indiv_us = (const float*)d_in[2];
    const float* edge_W   = (const float*)d_in[3];
    const float* edge_b   = (const float*)d_in[4];
    const float* wline1   = (const float*)d_in[5];
    const float* wline2   = (const float*)d_in[6];
    const float* hw1_w1 = (const float*)d_in[7];
    const float* hw1_b1 = (const float*)d_in[8];
    const float* hw1_w2 = (const float*)d_in[9];
    const float* hw1_b2 = (const float*)d_in[10];
    const float* hc1_w1 = (const float*)d_in[11];
    const float* hc1_b1 = (const float*)d_in[12];
    const float* hc1_w2 = (const float*)d_in[13];
    const float* hc1_b2 = (const float*)d_in[14];
    const float* hw_w1  = (const float*)d_in[15];
    const float* hw_b1  = (const float*)d_in[16];
    const float* hw_w2  = (const float*)d_in[17];
    const float* hw_b2  = (const float*)d_in[18];
    const float* hc_w1  = (const float*)d_in[19];
    const float* hc_b1  = (const float*)d_in[20];
    const float* hc_w2  = (const float*)d_in[21];
    const float* hc_b2  = (const float*)d_in[22];

    char* ws = (char*)d_ws;
    size_t o_states16 = 0;                                   // 33,554,432
    size_t o_W1t  = o_states16 + (size_t)BATCH * SDIM * 2;   // 2,097,152
    size_t o_b1   = o_W1t + (size_t)NH * SDIM * 2;           // 4096
    size_t o_W2t  = o_b1 + 4096;                             // 49,152
    size_t o_hcw2 = o_W2t + 49152;                           // 512
    size_t o_Pp   = o_hcw2 + 512;                            // 16384*104*4 = 6.8MB

    f16*   states16 = (f16*)(ws + o_states16);
    f16*   W1t      = (f16*)(ws + o_W1t);
    float* b1cat    = (float*)(ws + o_b1);
    f16*   W2t      = (f16*)(ws + o_W2t);
    f16*   hcw2     = (f16*)(ws + o_hcw2);
    float* Pp       = (float*)(ws + o_Pp);

    k_front<<<NB_FRONT, 256, 0, stream>>>(
        states,
        hw1_w1, hc1_w1, hw_w1, hc_w1, hw1_b1, hc1_b1, hw_b1, hc_b1,
        hw1_w2, hc1_w2, hw_w2, hc_w2,
        states16, W1t, b1cat, W2t, hcw2);
    k_gemm<<<256, 512, 0, stream>>>(states16, W1t, b1cat, W2t, hcw2, Pp);
    k_hgcn_ep<<<BATCH / 4, 256, 0, stream>>>(
        agent_qs, indiv_us, edge_W, edge_b, wline1, wline2, Pp,
        hw1_b2, hc1_b2, hw_b2, hc_b2, (float*)d_out);
}

// Round 7
// 120.616 us; speedup vs baseline: 1.2852x; 1.0288x over previous
//
#include <hip/hip_runtime.h>
#include <cstdint>

typedef _Float16 f16;
typedef _Float16 f16x2 __attribute__((ext_vector_type(2)));
typedef _Float16 f16x4 __attribute__((ext_vector_type(4)));
typedef _Float16 f16x8 __attribute__((ext_vector_type(8)));
typedef float f32x4 __attribute__((ext_vector_type(4)));

#define AS1U const __attribute__((address_space(1))) unsigned int
#define AS3U __attribute__((address_space(3))) unsigned int

__device__ __forceinline__ void gload_lds16(const void* g, void* l) {
    __builtin_amdgcn_global_load_lds((AS1U*)g, (AS3U*)l, 16, 0, 0);
}

// wave-local LDS sync: HGCN reduction state is per-wave (64 lanes, lockstep)
#define WSYNC() asm volatile("s_waitcnt lgkmcnt(0)" ::: "memory")
#define CFENCE() asm volatile("" ::: "memory")

#define BATCH 16384
#define NAG   32
#define OBS   96
#define SDIM  1024
#define NE    64
#define HIDN  256
#define NH    1024

// k_front grid layout (conv + packs)
#define NB_ST 1024
#define NB_PW 256
#define NB_SM 101
#define NB_FRONT (NB_ST + NB_PW + NB_SM)

// ======================= K_FRONT: states conv + weight packs =======================
__global__ __launch_bounds__(256) void k_front(
    const float* __restrict__ states,
    const float* __restrict__ w1a, const float* __restrict__ w1b,
    const float* __restrict__ w1c, const float* __restrict__ w1d,
    const float* __restrict__ b1a, const float* __restrict__ b1b,
    const float* __restrict__ b1c, const float* __restrict__ b1d,
    const float* __restrict__ w2a, const float* __restrict__ w2b,
    const float* __restrict__ w2c, const float* __restrict__ w2d,
    f16* __restrict__ states16, f16* __restrict__ W1t, float* __restrict__ b1cat,
    f16* __restrict__ W2t, f16* __restrict__ hcw2) {
    __shared__ float tile[64 * 65];
    const int tid = threadIdx.x;
    int bid = blockIdx.x;

    if (bid < NB_ST) {                    // states fp32 -> fp16
        int i = bid * 256 + tid;
        const int n4 = BATCH * SDIM / 4;
        const int stride = NB_ST * 256;
        for (; i < n4; i += stride) {
            float4 v = ((const float4*)states)[i];
            f16x4 h = { (f16)v.x, (f16)v.y, (f16)v.z, (f16)v.w };
            ((f16x4*)states16)[i] = h;
        }
        return;
    }
    bid -= NB_ST;
    if (bid < NB_PW) {                    // W1 pack via LDS transpose (coalesced both sides)
        int mlp = bid >> 6, rem = bid & 63, kt = rem >> 2, ct = rem & 3;
        const float* src = (mlp == 0) ? w1a : (mlp == 1) ? w1b : (mlp == 2) ? w1c : w1d;
        int k0 = kt * 64, c0 = ct * 64;
        for (int i = tid; i < 4096; i += 256) {
            int kk = i >> 6, cc = i & 63;
            tile[kk * 65 + cc] = src[(size_t)(k0 + kk) * 256 + c0 + cc];
        }
        __syncthreads();
        for (int i = tid; i < 4096; i += 256) {
            int cc = i >> 6, kk = i & 63;
            W1t[(size_t)(mlp * 256 + c0 + cc) * 1024 + k0 + kk] = (f16)tile[kk * 65 + cc];
        }
        return;
    }
    bid -= NB_PW;
    {                                     // W2t, hcw2, b1cat
        int i = bid * 256 + tid;
        if (i < 24576) {
            int mp = i >> 13, rem = i & 8191, oo = rem >> 8, kk = rem & 255;
            const float* src = (mp == 0) ? w2a : (mp == 1) ? w2b : w2c;
            W2t[i] = (f16)src[kk * 32 + oo];
        } else if (i < 24832) {
            int k = i - 24576;
            hcw2[k] = (f16)w2d[k];
        } else if (i < 25856) {
            int n = i - 24832;
            int mlp = n >> 8, c = n & 255;
            const float* bsrc = (mlp == 0) ? b1a : (mlp == 1) ? b1b : (mlp == 2) ? b1c : b1d;
            b1cat[n] = bsrc[c];
        }
    }
}

// ======================= K_GEMM: 256x256 counted-vmcnt dbuf + T2 swizzle + T5 =======================
// T4: loads stay in flight across barriers (vmcnt(8) per kt, never 0 until tail).
// T2: LDS chunk swizzle c ^= row&7, applied via pre-swizzled GLOBAL source (linear
//     gload_lds dest) + swizzled ds_read address (rule #21; numerics validated R2).
__global__ __launch_bounds__(512) void k_gemm(
    const f16* __restrict__ A, const f16* __restrict__ B,
    const float* __restrict__ b1cat, const f16* __restrict__ W2t,
    const f16* __restrict__ hcw2, float* __restrict__ Pp) {
    __shared__ __align__(16) char smem[131072];
    f16* Asb = (f16*)smem;                  // [2][256][64] (chunk-swizzled rows)
    f16* Bsb = (f16*)(smem + 65536);        // [2][256][64]
    f16* Ts  = (f16*)smem;                  // [128][264] relu'd half-tile (after K-loop)

    const int tid = threadIdx.x;
    const int w = tid >> 6, l = tid & 63;
    const int lm = l & 15, lk = l >> 4;
    const int wm = w >> 2, wn = w & 3;      // 2M x 4N waves
    // XCD map: 4 same-mt blocks (nt fast) adjacent per XCD -> shared A panel in L2
    const int p = blockIdx.x;
    const int xcd = p & 7, s = p >> 3;
    const int mt = xcd * 8 + (s >> 2);      // 0..63
    const int nt = s & 3;                   // 0..3 == mlp
    const int m0 = mt * 256, n0 = nt * 256;
    const int c0 = w * 4;                   // first staging chunk-row (of 32 per operand)
    const int srow = l >> 3;                // row within 8-row chunk-row (== row&7)
    const int gchunk = (l & 7) ^ srow;      // pre-swizzled global 16B-chunk

    // epilogue bias loaded BEFORE staging so the vmcnt ledger stays pure
    float bj[4];
    #pragma unroll
    for (int j = 0; j < 4; j++) bj[j] = b1cat[n0 + wn * 64 + j * 16 + lm];

    f32x4 acc[8][4];
    #pragma unroll
    for (int i = 0; i < 8; i++)
        #pragma unroll
        for (int j = 0; j < 4; j++) acc[i][j] = (f32x4){0.f, 0.f, 0.f, 0.f};

#define STAGE(KT, BI)                                                                     \
    {                                                                                     \
        f16* Ad = Asb + (BI) * 16384;                                                     \
        f16* Bd = Bsb + (BI) * 16384;                                                     \
        _Pragma("unroll")                                                                 \
        for (int i_ = 0; i_ < 4; i_++) {                                                  \
            int cc = c0 + i_;                                                             \
            gload_lds16(&A[(size_t)(m0 + cc * 8 + srow) * 1024 + (KT) * 64 + gchunk * 8], \
                        &Ad[cc * 512]);                                                   \
            gload_lds16(&B[(size_t)(n0 + cc * 8 + srow) * 1024 + (KT) * 64 + gchunk * 8], \
                        &Bd[cc * 512]);                                                   \
        }                                                                                 \
    }

    // prologue: 2 tiles in flight (16 loads/thread)
    STAGE(0, 0);
    STAGE(1, 1);

    for (int kt = 0; kt < 16; kt++) {
        if (kt < 15) { asm volatile("s_waitcnt vmcnt(8)" ::: "memory"); }
        else         { asm volatile("s_waitcnt vmcnt(0)" ::: "memory"); }
        CFENCE(); __builtin_amdgcn_s_barrier(); CFENCE();   // tile kt landed block-wide

        const f16* As_ = Asb + (kt & 1) * 16384;
        const f16* Bs_ = Bsb + (kt & 1) * 16384;
        __builtin_amdgcn_s_setprio(1);
        #pragma unroll
        for (int ks = 0; ks < 2; ks++) {
            const int sw = (((ks * 4 + lk) ^ (lm & 7)) << 3);   // swizzled 16B slot
            f16x8 af[8], bf[4];
            #pragma unroll
            for (int i = 0; i < 8; i++)
                af[i] = *(const f16x8*)&As_[(wm * 128 + i * 16 + lm) * 64 + sw];
            #pragma unroll
            for (int j = 0; j < 4; j++)
                bf[j] = *(const f16x8*)&Bs_[(wn * 64 + j * 16 + lm) * 64 + sw];
            #pragma unroll
            for (int i = 0; i < 8; i++)
                #pragma unroll
                for (int j = 0; j < 4; j++)
                    acc[i][j] = __builtin_amdgcn_mfma_f32_16x16x32_f16(af[i], bf[j], acc[i][j], 0, 0, 0);
        }
        __builtin_amdgcn_s_setprio(0);

        CFENCE(); __builtin_amdgcn_s_barrier(); CFENCE();   // all reads of buf done
        if (kt < 14) STAGE(kt + 2, kt & 1);                 // overwrite just-read buffer
    }
#undef STAGE

    // ---- epilogue: bias+relu -> Ts, layer-2 per 128-row pass; block covers FULL mlp (K=256) ----
    const int mlp = nt;
    #pragma unroll
    for (int pass = 0; pass < 2; pass++) {
        if (wm == pass) {
            #pragma unroll
            for (int i = 0; i < 8; i++)
                #pragma unroll
                for (int r = 0; r < 4; r++) {
                    int rl = i * 16 + lk * 4 + r;
                    #pragma unroll
                    for (int j = 0; j < 4; j++) {
                        float v = acc[i][j][r] + bj[j];
                        Ts[rl * 264 + wn * 64 + j * 16 + lm] = (f16)(v > 0.f ? v : 0.f);
                    }
                }
        }
        __syncthreads();
        const int grow = m0 + pass * 128 + w * 16;
        if (mlp < 3) {
            const f16* wb = W2t + mlp * 8192;
            f32x4 acc2[2];
            acc2[0] = (f32x4){0, 0, 0, 0}; acc2[1] = (f32x4){0, 0, 0, 0};
            #pragma unroll
            for (int ks = 0; ks < 8; ks++) {
                f16x8 a  = *(const f16x8*)&Ts[(w * 16 + lm) * 264 + ks * 32 + lk * 8];
                f16x8 b0 = *(const f16x8*)&wb[lm * 256 + ks * 32 + lk * 8];
                f16x8 b1 = *(const f16x8*)&wb[(16 + lm) * 256 + ks * 32 + lk * 8];
                acc2[0] = __builtin_amdgcn_mfma_f32_16x16x32_f16(a, b0, acc2[0], 0, 0, 0);
                acc2[1] = __builtin_amdgcn_mfma_f32_16x16x32_f16(a, b1, acc2[1], 0, 0, 0);
            }
            #pragma unroll
            for (int j2 = 0; j2 < 2; j2++)
                #pragma unroll
                for (int r = 0; r < 4; r++)
                    Pp[(size_t)(grow + lk * 4 + r) * 104 + mlp * 32 + j2 * 16 + lm] = acc2[j2][r];
        } else {
            f32x4 acc2 = (f32x4){0, 0, 0, 0};
            #pragma unroll
            for (int ks = 0; ks < 8; ks++) {
                f16x8 a = *(const f16x8*)&Ts[(w * 16 + lm) * 264 + ks * 32 + lk * 8];
                f16x8 bz = (f16x8){0, 0, 0, 0, 0, 0, 0, 0};
                if (lm == 0) bz = *(const f16x8*)&hcw2[ks * 32 + lk * 8];
                acc2 = __builtin_amdgcn_mfma_f32_16x16x32_f16(a, bz, acc2, 0, 0, 0);
            }
            if (lm == 0)
                #pragma unroll
                for (int r = 0; r < 4; r++)
                    Pp[(size_t)(grow + lk * 4 + r) * 104 + 96] = acc2[r];
        }
        if (pass == 0) __syncthreads();      // protect Ts before pass-1 overwrite
    }
}

// ======================= K_HGCN_EP: HGCN + fused mix epilogue (f32 aux, single Pp) =======================
__global__ __launch_bounds__(256) void k_hgcn_ep(
    const float* __restrict__ agent_qs, const float* __restrict__ indiv_us,
    const float* __restrict__ edge_W, const float* __restrict__ edge_b,
    const float* __restrict__ wline1, const float* __restrict__ wline2,
    const float* __restrict__ Pp,
    const float* __restrict__ hw1_b2, const float* __restrict__ hc1_b2,
    const float* __restrict__ hw_b2, const float* __restrict__ hc_b2,
    float* __restrict__ out) {
    // arena: eWs 13312 | swa 512 | Hs(f16) 16896 | sv 1024 | stt 512 | sdis 1024 | sbinv 1024 = 34304
    __shared__ __align__(16) char arena[34304];
    f16*   eWs   = (f16*)arena;
    float* swa   = (float*)(arena + 13312);
    f16*   HsB   = (f16*)(arena + 13824);
    float* svB   = (float*)(arena + 30720);
    float* sttB  = (float*)(arena + 31744);
    float* sdisB = (float*)(arena + 32256);
    float* sbinvB= (float*)(arena + 33280);

    const int tid = threadIdx.x;
    const int w = tid >> 6, l = tid & 63;
    const int b = blockIdx.x * 4 + w;
    f16*   Hw    = HsB + w * (32 * 66);
    float* sv    = svB + w * 64;
    float* stt   = sttB + w * 32;
    float* sdis  = sdisB + w * 64;
    float* sbinv = sbinvB + w * 64;

    const int nn = l & 31, half = l >> 5;

    // T14: issue epilogue loads early (lanes 0-31), consume after y2
    float pa0 = 0.f, pc0 = 0.f, pw0 = 0.f;
    float p96a = 0.f, bw1 = 0.f, bc1 = 0.f, bww = 0.f, bhc = 0.f;
    if (half == 0) {
        const float* p0 = Pp + (size_t)b * 104;
        pa0 = p0[nn];
        pc0 = p0[32 + nn];
        pw0 = p0[64 + nn];
        p96a = p0[96];
        bw1 = hw1_b2[nn];  bc1 = hc1_b2[nn];
        bww = hw_b2[nn];   bhc = hc_b2[0];
    }
    float q = agent_qs[(size_t)b * 32 + nn];

    // inline edge_W transpose: edge_W[k][n] -> eWs[n][k]
    for (int i = tid; i < 6144; i += 256) {
        int k = i >> 6, n = i & 63;
        eWs[n * 104 + k] = (f16)edge_W[i];
    }
    if (tid < 64) swa[tid] = fabsf(wline1[tid]);
    else if (tid < 128) swa[tid] = fabsf(wline2[tid - 64]);
    __syncthreads();   // the only block-wide barrier (eWs/swa are cross-wave)

    const int lm = l & 15, lk = l >> 4;
    const float* ub = indiv_us + (size_t)b * (NAG * OBS);

    // H = relu(u @ W^T + b)
    #pragma unroll
    for (int mt = 0; mt < 2; mt++) {
        f16x8 af[3];
        #pragma unroll
        for (int ks = 0; ks < 3; ks++) {
            const float* up = ub + (mt * 16 + lm) * 96 + ks * 32 + lk * 8;
            float4 v0 = *(const float4*)up;
            float4 v1 = *(const float4*)(up + 4);
            af[ks] = (f16x8){ (f16)v0.x, (f16)v0.y, (f16)v0.z, (f16)v0.w,
                              (f16)v1.x, (f16)v1.y, (f16)v1.z, (f16)v1.w };
        }
        #pragma unroll
        for (int nt = 0; nt < 4; nt++) {
            f32x4 acc = {0.f, 0.f, 0.f, 0.f};
            #pragma unroll
            for (int ks = 0; ks < 3; ks++) {
                f16x8 bb = *(const f16x8*)&eWs[(nt * 16 + lm) * 104 + ks * 32 + lk * 8];
                acc = __builtin_amdgcn_mfma_f32_16x16x32_f16(af[ks], bb, acc, 0, 0, 0);
            }
            int col = nt * 16 + lm;
            float bias = edge_b[col];
            #pragma unroll
            for (int r = 0; r < 4; r++) {
                int row = mt * 16 + lk * 4 + r;
                float hv = acc[r] + bias;
                Hw[row * 66 + col] = (f16)(hv > 0.f ? hv : 0.f);
            }
        }
    }
    WSYNC();

    float bsum = 0.f;
    #pragma unroll
    for (int n = 0; n < 32; n++) bsum += (float)Hw[n * 66 + l];
    sbinv[l] = bsum > 0.f ? 1.f / bsum : 0.f;

    float dd = 0.f;
    #pragma unroll 8
    for (int e2 = 0; e2 < 32; e2++) {
        f16x2 h2 = *(const f16x2*)&Hw[nn * 66 + e2 * 2];
        dd += (float)h2.x * swa[half * 64 + e2 * 2] + (float)h2.y * swa[half * 64 + e2 * 2 + 1];
    }
    float dis = dd > 0.f ? rsqrtf(dd) : 0.f;
    sdis[l] = dis;
    if (half == 0) stt[nn] = dis * q;
    WSYNC();

    float s1 = 0.f;
    #pragma unroll
    for (int n = 0; n < 32; n++) s1 += (float)Hw[n * 66 + l] * stt[n];
    sv[l] = s1 * swa[l] * sbinv[l];
    WSYNC();

    float y1 = 0.f;
    #pragma unroll 8
    for (int e2 = 0; e2 < 32; e2++) {
        f16x2 h2 = *(const f16x2*)&Hw[nn * 66 + e2 * 2];
        y1 += (float)h2.x * sv[e2 * 2] + (float)h2.y * sv[e2 * 2 + 1];
    }
    float x2 = sdis[nn] * y1;
    if (half == 0) stt[nn] = sdis[32 + nn] * x2;
    WSYNC();

    float s2 = 0.f;
    #pragma unroll
    for (int n = 0; n < 32; n++) s2 += (float)Hw[n * 66 + l] * stt[n];
    sv[l] = s2 * swa[64 + l] * sbinv[l];
    WSYNC();

    float y2 = 0.f;
    #pragma unroll 8
    for (int e2 = 0; e2 < 32; e2++) {
        f16x2 h2 = *(const f16x2*)&Hw[nn * 66 + e2 * 2];
        y2 += (float)h2.x * sv[e2 * 2] + (float)h2.y * sv[e2 * 2 + 1];
    }

    // ---- fused mix epilogue (lanes 0-31 of each wave) ----
    float qsv = sdis[32 + nn] * y2;
    float w1v = fabsf(pa0 + bw1);
    float c1v = pc0 + bc1;
    float wwv = fabsf(pw0 + bww);
    float z = qsv * w1v + c1v;
    float qt = z > 0.f ? z : expm1f(z);
    float val = (half == 0) ? qt * wwv : 0.f;
    val += __shfl_xor(val, 1, 32);
    val += __shfl_xor(val, 2, 32);
    val += __shfl_xor(val, 4, 32);
    val += __shfl_xor(val, 8, 32);
    val += __shfl_xor(val, 16, 32);
    if (l == 0) out[b] = val + p96a + bhc;
}

// ======================= launch =======================
extern "C" void kernel_launch(void* const* d_in, const int* in_sizes, int n_in,
                              void* d_out, int out_size, void* d_ws, size_t ws_size,
                              hipStream_t stream) {
    const float* agent_qs = (const float*)d_in[0];
    const float* states   = (const float*)d_in[1];
    const float* indiv_us = (const float*)d_in[2];
    const float* edge_W   = (const float*)d_in[3];
    const float* edge_b   = (const float*)d_in[4];
    const float* wline1   = (const float*)d_in[5];
    const float* wline2   = (const float*)d_in[6];
    const float* hw1_w1 = (const float*)d_in[7];
    const float* hw1_b1 = (const float*)d_in[8];
    const float* hw1_w2 = (const float*)d_in[9];
    const float* hw1_b2 = (const float*)d_in[10];
    const float* hc1_w1 = (const float*)d_in[11];
    const float* hc1_b1 = (const float*)d_in[12];
    const float* hc1_w2 = (const float*)d_in[13];
    const float* hc1_b2 = (const float*)d_in[14];
    const float* hw_w1  = (const float*)d_in[15];
    const float* hw_b1  = (const float*)d_in[16];
    const float* hw_w2  = (const float*)d_in[17];
    const float* hw_b2  = (const float*)d_in[18];
    const float* hc_w1  = (const float*)d_in[19];
    const float* hc_b1  = (const float*)d_in[20];
    const float* hc_w2  = (const float*)d_in[21];
    const float* hc_b2  = (const float*)d_in[22];

    char* ws = (char*)d_ws;
    size_t o_states16 = 0;                                   // 33,554,432
    size_t o_W1t  = o_states16 + (size_t)BATCH * SDIM * 2;   // 2,097,152
    size_t o_b1   = o_W1t + (size_t)NH * SDIM * 2;           // 4096
    size_t o_W2t  = o_b1 + 4096;                             // 49,152
    size_t o_hcw2 = o_W2t + 49152;                           // 512
    size_t o_Pp   = o_hcw2 + 512;                            // 16384*104*4 = 6.8MB

    f16*   states16 = (f16*)(ws + o_states16);
    f16*   W1t      = (f16*)(ws + o_W1t);
    float* b1cat    = (float*)(ws + o_b1);
    f16*   W2t      = (f16*)(ws + o_W2t);
    f16*   hcw2     = (f16*)(ws + o_hcw2);
    float* Pp       = (float*)(ws + o_Pp);

    k_front<<<NB_FRONT, 256, 0, stream>>>(
        states,
        hw1_w1, hc1_w1, hw_w1, hc_w1, hw1_b1, hc1_b1, hw_b1, hc_b1,
        hw1_w2, hc1_w2, hw_w2, hc_w2,
        states16, W1t, b1cat, W2t, hcw2);
    k_gemm<<<256, 512, 0, stream>>>(states16, W1t, b1cat, W2t, hcw2, Pp);
    k_hgcn_ep<<<BATCH / 4, 256, 0, stream>>>(
        agent_qs, indiv_us, edge_W, edge_b, wline1, wline2, Pp,
        hw1_b2, hc1_b2, hw_b2, hc_b2, (float*)d_out);
}

// Round 8
// 120.392 us; speedup vs baseline: 1.2876x; 1.0019x over previous
//
#include <hip/hip_runtime.h>
#include <cstdint>

typedef _Float16 f16;
typedef _Float16 f16x2 __attribute__((ext_vector_type(2)));
typedef _Float16 f16x4 __attribute__((ext_vector_type(4)));
typedef _Float16 f16x8 __attribute__((ext_vector_type(8)));
typedef float f32x4 __attribute__((ext_vector_type(4)));

#define AS1U const __attribute__((address_space(1))) unsigned int
#define AS3U __attribute__((address_space(3))) unsigned int

__device__ __forceinline__ void gload_lds16(const void* g, void* l) {
    __builtin_amdgcn_global_load_lds((AS1U*)g, (AS3U*)l, 16, 0, 0);
}

// wave-local LDS sync: HGCN reduction state is per-wave (64 lanes, lockstep)
#define WSYNC() asm volatile("s_waitcnt lgkmcnt(0)" ::: "memory")
#define CFENCE() asm volatile("" ::: "memory")

#define BATCH 16384
#define NAG   32
#define OBS   96
#define SDIM  1024
#define NE    64
#define HIDN  256
#define NH    1024

// k_front grid layout (conv + packs)
#define NB_ST 1024
#define NB_PW 256
#define NB_SM 101
#define NB_FRONT (NB_ST + NB_PW + NB_SM)

// ======================= K_FRONT: states conv + weight packs =======================
__global__ __launch_bounds__(256) void k_front(
    const float* __restrict__ states,
    const float* __restrict__ w1a, const float* __restrict__ w1b,
    const float* __restrict__ w1c, const float* __restrict__ w1d,
    const float* __restrict__ b1a, const float* __restrict__ b1b,
    const float* __restrict__ b1c, const float* __restrict__ b1d,
    const float* __restrict__ w2a, const float* __restrict__ w2b,
    const float* __restrict__ w2c, const float* __restrict__ w2d,
    f16* __restrict__ states16, f16* __restrict__ W1t, float* __restrict__ b1cat,
    f16* __restrict__ W2t, f16* __restrict__ hcw2) {
    __shared__ float tile[64 * 65];
    const int tid = threadIdx.x;
    int bid = blockIdx.x;

    if (bid < NB_ST) {                    // states fp32 -> fp16
        int i = bid * 256 + tid;
        const int n4 = BATCH * SDIM / 4;
        const int stride = NB_ST * 256;
        for (; i < n4; i += stride) {
            float4 v = ((const float4*)states)[i];
            f16x4 h = { (f16)v.x, (f16)v.y, (f16)v.z, (f16)v.w };
            ((f16x4*)states16)[i] = h;
        }
        return;
    }
    bid -= NB_ST;
    if (bid < NB_PW) {                    // W1 pack via LDS transpose (coalesced both sides)
        int mlp = bid >> 6, rem = bid & 63, kt = rem >> 2, ct = rem & 3;
        const float* src = (mlp == 0) ? w1a : (mlp == 1) ? w1b : (mlp == 2) ? w1c : w1d;
        int k0 = kt * 64, c0 = ct * 64;
        for (int i = tid; i < 4096; i += 256) {
            int kk = i >> 6, cc = i & 63;
            tile[kk * 65 + cc] = src[(size_t)(k0 + kk) * 256 + c0 + cc];
        }
        __syncthreads();
        for (int i = tid; i < 4096; i += 256) {
            int cc = i >> 6, kk = i & 63;
            W1t[(size_t)(mlp * 256 + c0 + cc) * 1024 + k0 + kk] = (f16)tile[kk * 65 + cc];
        }
        return;
    }
    bid -= NB_PW;
    {                                     // W2t, hcw2, b1cat
        int i = bid * 256 + tid;
        if (i < 24576) {
            int mp = i >> 13, rem = i & 8191, oo = rem >> 8, kk = rem & 255;
            const float* src = (mp == 0) ? w2a : (mp == 1) ? w2b : w2c;
            W2t[i] = (f16)src[kk * 32 + oo];
        } else if (i < 24832) {
            int k = i - 24576;
            hcw2[k] = (f16)w2d[k];
        } else if (i < 25856) {
            int n = i - 24832;
            int mlp = n >> 8, c = n & 255;
            const float* bsrc = (mlp == 0) ? b1a : (mlp == 1) ? b1b : (mlp == 2) ? b1c : b1d;
            b1cat[n] = bsrc[c];
        }
    }
}

// ======================= K_GEMM: 256x256, 4-quadrant phase interleave (m201 port) =======================
// Per kt: entry {vmcnt(8); barrier} then 4 phases, each {ds_read subtile | STAGE} ->
// setprio(1) 16 MFMA setprio(0) -> barrier. Loads never drain (T4); chunk-XOR LDS
// swizzle via pre-swizzled global source (T2, rule #21); staging rides phase D after
// phase C's barrier proves all reads of the target buffer retired.
__global__ __launch_bounds__(512) void k_gemm(
    const f16* __restrict__ A, const f16* __restrict__ B,
    const float* __restrict__ b1cat, const f16* __restrict__ W2t,
    const f16* __restrict__ hcw2, float* __restrict__ Pp) {
    __shared__ __align__(16) char smem[131072];
    f16* Asb = (f16*)smem;                  // [2][256][64] (chunk-swizzled rows)
    f16* Bsb = (f16*)(smem + 65536);        // [2][256][64]
    f16* Ts  = (f16*)smem;                  // [128][264] relu'd half-tile (after K-loop)

    const int tid = threadIdx.x;
    const int w = tid >> 6, l = tid & 63;
    const int lm = l & 15, lk = l >> 4;
    const int wm = w >> 2, wn = w & 3;      // 2M x 4N waves
    // XCD map: 4 same-mt blocks (nt fast) adjacent per XCD -> shared A panel in L2
    const int p = blockIdx.x;
    const int xcd = p & 7, s = p >> 3;
    const int mt = xcd * 8 + (s >> 2);      // 0..63
    const int nt = s & 3;                   // 0..3 == mlp
    const int m0 = mt * 256, n0 = nt * 256;
    const int c0 = w * 4;                   // first staging chunk-row (of 32 per operand)
    const int srow = l >> 3;                // row within 8-row chunk-row
    const int gchunk = (l & 7) ^ srow;      // pre-swizzled global 16B-chunk

    // epilogue bias loaded BEFORE staging so the vmcnt ledger stays pure
    float bj[4];
    #pragma unroll
    for (int j = 0; j < 4; j++) bj[j] = b1cat[n0 + wn * 64 + j * 16 + lm];

    f32x4 acc[8][4];
    #pragma unroll
    for (int i = 0; i < 8; i++)
        #pragma unroll
        for (int j = 0; j < 4; j++) acc[i][j] = (f32x4){0.f, 0.f, 0.f, 0.f};

#define STAGE(KT, BI)                                                                     \
    {                                                                                     \
        f16* Ad = Asb + (BI) * 16384;                                                     \
        f16* Bd = Bsb + (BI) * 16384;                                                     \
        _Pragma("unroll")                                                                 \
        for (int i_ = 0; i_ < 4; i_++) {                                                  \
            int cc = c0 + i_;                                                             \
            gload_lds16(&A[(size_t)(m0 + cc * 8 + srow) * 1024 + (KT) * 64 + gchunk * 8], \
                        &Ad[cc * 512]);                                                   \
            gload_lds16(&B[(size_t)(n0 + cc * 8 + srow) * 1024 + (KT) * 64 + gchunk * 8], \
                        &Bd[cc * 512]);                                                   \
        }                                                                                 \
    }

    // prologue: 2 tiles in flight (16 loads/thread)
    STAGE(0, 0);
    STAGE(1, 1);

    for (int kt = 0; kt < 16; kt++) {
        if (kt < 15) { asm volatile("s_waitcnt vmcnt(8)" ::: "memory"); }
        else         { asm volatile("s_waitcnt vmcnt(0)" ::: "memory"); }
        CFENCE(); __builtin_amdgcn_s_barrier(); CFENCE();   // tile kt landed block-wide

        const f16* As_ = Asb + (kt & 1) * 16384;
        const f16* Bs_ = Bsb + (kt & 1) * 16384;
        const int swlo = ((lk ^ (lm & 7)) << 3);            // ks=0 swizzled 16B slot
        const int swhi = (((4 + lk) ^ (lm & 7)) << 3);      // ks=1

        f16x8 af[4][2], bf01[2][2], bf23[2][2];

        // ---- phase A: read af_lo + bf01, MFMA q0 (rows 0-3 x cols 0-1) ----
        #pragma unroll
        for (int i = 0; i < 4; i++) {
            af[i][0] = *(const f16x8*)&As_[(wm * 128 + i * 16 + lm) * 64 + swlo];
            af[i][1] = *(const f16x8*)&As_[(wm * 128 + i * 16 + lm) * 64 + swhi];
        }
        #pragma unroll
        for (int j = 0; j < 2; j++) {
            bf01[j][0] = *(const f16x8*)&Bs_[(wn * 64 + j * 16 + lm) * 64 + swlo];
            bf01[j][1] = *(const f16x8*)&Bs_[(wn * 64 + j * 16 + lm) * 64 + swhi];
        }
        __builtin_amdgcn_s_setprio(1);
        #pragma unroll
        for (int ks = 0; ks < 2; ks++)
            #pragma unroll
            for (int i = 0; i < 4; i++)
                #pragma unroll
                for (int j = 0; j < 2; j++)
                    acc[i][j] = __builtin_amdgcn_mfma_f32_16x16x32_f16(af[i][ks], bf01[j][ks], acc[i][j], 0, 0, 0);
        __builtin_amdgcn_s_setprio(0);
        CFENCE(); __builtin_amdgcn_s_barrier(); CFENCE();

        // ---- phase B: read bf23, MFMA q1 (rows 0-3 x cols 2-3) ----
        #pragma unroll
        for (int j = 0; j < 2; j++) {
            bf23[j][0] = *(const f16x8*)&Bs_[(wn * 64 + (2 + j) * 16 + lm) * 64 + swlo];
            bf23[j][1] = *(const f16x8*)&Bs_[(wn * 64 + (2 + j) * 16 + lm) * 64 + swhi];
        }
        __builtin_amdgcn_s_setprio(1);
        #pragma unroll
        for (int ks = 0; ks < 2; ks++)
            #pragma unroll
            for (int i = 0; i < 4; i++)
                #pragma unroll
                for (int j = 0; j < 2; j++)
                    acc[i][2 + j] = __builtin_amdgcn_mfma_f32_16x16x32_f16(af[i][ks], bf23[j][ks], acc[i][2 + j], 0, 0, 0);
        __builtin_amdgcn_s_setprio(0);
        CFENCE(); __builtin_amdgcn_s_barrier(); CFENCE();

        // ---- phase C: read af_hi (overwrite af), MFMA q2 (rows 4-7 x cols 0-1) ----
        #pragma unroll
        for (int i = 0; i < 4; i++) {
            af[i][0] = *(const f16x8*)&As_[(wm * 128 + (4 + i) * 16 + lm) * 64 + swlo];
            af[i][1] = *(const f16x8*)&As_[(wm * 128 + (4 + i) * 16 + lm) * 64 + swhi];
        }
        __builtin_amdgcn_s_setprio(1);
        #pragma unroll
        for (int ks = 0; ks < 2; ks++)
            #pragma unroll
            for (int i = 0; i < 4; i++)
                #pragma unroll
                for (int j = 0; j < 2; j++)
                    acc[4 + i][j] = __builtin_amdgcn_mfma_f32_16x16x32_f16(af[i][ks], bf01[j][ks], acc[4 + i][j], 0, 0, 0);
        __builtin_amdgcn_s_setprio(0);
        CFENCE(); __builtin_amdgcn_s_barrier(); CFENCE();   // ALL reads of buf kt&1 retired

        // ---- phase D: STAGE(kt+2) into just-freed buffer, MFMA q3 (rows 4-7 x cols 2-3) ----
        if (kt < 14) STAGE(kt + 2, kt & 1);
        __builtin_amdgcn_s_setprio(1);
        #pragma unroll
        for (int ks = 0; ks < 2; ks++)
            #pragma unroll
            for (int i = 0; i < 4; i++)
                #pragma unroll
                for (int j = 0; j < 2; j++)
                    acc[4 + i][2 + j] = __builtin_amdgcn_mfma_f32_16x16x32_f16(af[i][ks], bf23[j][ks], acc[4 + i][2 + j], 0, 0, 0);
        __builtin_amdgcn_s_setprio(0);
        // no barrier here: next-kt entry {vmcnt; barrier} provides the ordering
    }
#undef STAGE

    __syncthreads();   // drain before Ts aliases Asb

    // ---- epilogue: bias+relu -> Ts, layer-2 per 128-row pass; block covers FULL mlp (K=256) ----
    const int mlp = nt;
    #pragma unroll
    for (int pass = 0; pass < 2; pass++) {
        if (wm == pass) {
            #pragma unroll
            for (int i = 0; i < 8; i++)
                #pragma unroll
                for (int r = 0; r < 4; r++) {
                    int rl = i * 16 + lk * 4 + r;
                    #pragma unroll
                    for (int j = 0; j < 4; j++) {
                        float v = acc[i][j][r] + bj[j];
                        Ts[rl * 264 + wn * 64 + j * 16 + lm] = (f16)(v > 0.f ? v : 0.f);
                    }
                }
        }
        __syncthreads();
        const int grow = m0 + pass * 128 + w * 16;
        if (mlp < 3) {
            const f16* wb = W2t + mlp * 8192;
            f32x4 acc2[2];
            acc2[0] = (f32x4){0, 0, 0, 0}; acc2[1] = (f32x4){0, 0, 0, 0};
            #pragma unroll
            for (int ks = 0; ks < 8; ks++) {
                f16x8 a  = *(const f16x8*)&Ts[(w * 16 + lm) * 264 + ks * 32 + lk * 8];
                f16x8 b0 = *(const f16x8*)&wb[lm * 256 + ks * 32 + lk * 8];
                f16x8 b1 = *(const f16x8*)&wb[(16 + lm) * 256 + ks * 32 + lk * 8];
                acc2[0] = __builtin_amdgcn_mfma_f32_16x16x32_f16(a, b0, acc2[0], 0, 0, 0);
                acc2[1] = __builtin_amdgcn_mfma_f32_16x16x32_f16(a, b1, acc2[1], 0, 0, 0);
            }
            #pragma unroll
            for (int j2 = 0; j2 < 2; j2++)
                #pragma unroll
                for (int r = 0; r < 4; r++)
                    Pp[(size_t)(grow + lk * 4 + r) * 104 + mlp * 32 + j2 * 16 + lm] = acc2[j2][r];
        } else {
            f32x4 acc2 = (f32x4){0, 0, 0, 0};
            #pragma unroll
            for (int ks = 0; ks < 8; ks++) {
                f16x8 a = *(const f16x8*)&Ts[(w * 16 + lm) * 264 + ks * 32 + lk * 8];
                f16x8 bz = (f16x8){0, 0, 0, 0, 0, 0, 0, 0};
                if (lm == 0) bz = *(const f16x8*)&hcw2[ks * 32 + lk * 8];
                acc2 = __builtin_amdgcn_mfma_f32_16x16x32_f16(a, bz, acc2, 0, 0, 0);
            }
            if (lm == 0)
                #pragma unroll
                for (int r = 0; r < 4; r++)
                    Pp[(size_t)(grow + lk * 4 + r) * 104 + 96] = acc2[r];
        }
        if (pass == 0) __syncthreads();      // protect Ts before pass-1 overwrite
    }
}

// ======================= K_HGCN_EP: HGCN + fused mix epilogue (f32 aux, single Pp) =======================
__global__ __launch_bounds__(256) void k_hgcn_ep(
    const float* __restrict__ agent_qs, const float* __restrict__ indiv_us,
    const float* __restrict__ edge_W, const float* __restrict__ edge_b,
    const float* __restrict__ wline1, const float* __restrict__ wline2,
    const float* __restrict__ Pp,
    const float* __restrict__ hw1_b2, const float* __restrict__ hc1_b2,
    const float* __restrict__ hw_b2, const float* __restrict__ hc_b2,
    float* __restrict__ out) {
    // arena: eWs 13312 | swa 512 | Hs(f16) 16896 | sv 1024 | stt 512 | sdis 1024 | sbinv 1024 = 34304
    __shared__ __align__(16) char arena[34304];
    f16*   eWs   = (f16*)arena;
    float* swa   = (float*)(arena + 13312);
    f16*   HsB   = (f16*)(arena + 13824);
    float* svB   = (float*)(arena + 30720);
    float* sttB  = (float*)(arena + 31744);
    float* sdisB = (float*)(arena + 32256);
    float* sbinvB= (float*)(arena + 33280);

    const int tid = threadIdx.x;
    const int w = tid >> 6, l = tid & 63;
    const int b = blockIdx.x * 4 + w;
    f16*   Hw    = HsB + w * (32 * 66);
    float* sv    = svB + w * 64;
    float* stt   = sttB + w * 32;
    float* sdis  = sdisB + w * 64;
    float* sbinv = sbinvB + w * 64;

    const int nn = l & 31, half = l >> 5;

    // T14: issue epilogue loads early (lanes 0-31), consume after y2
    float pa0 = 0.f, pc0 = 0.f, pw0 = 0.f;
    float p96a = 0.f, bw1 = 0.f, bc1 = 0.f, bww = 0.f, bhc = 0.f;
    if (half == 0) {
        const float* p0 = Pp + (size_t)b * 104;
        pa0 = p0[nn];
        pc0 = p0[32 + nn];
        pw0 = p0[64 + nn];
        p96a = p0[96];
        bw1 = hw1_b2[nn];  bc1 = hc1_b2[nn];
        bww = hw_b2[nn];   bhc = hc_b2[0];
    }
    float q = agent_qs[(size_t)b * 32 + nn];

    // inline edge_W transpose: edge_W[k][n] -> eWs[n][k]
    for (int i = tid; i < 6144; i += 256) {
        int k = i >> 6, n = i & 63;
        eWs[n * 104 + k] = (f16)edge_W[i];
    }
    if (tid < 64) swa[tid] = fabsf(wline1[tid]);
    else if (tid < 128) swa[tid] = fabsf(wline2[tid - 64]);
    __syncthreads();   // the only block-wide barrier (eWs/swa are cross-wave)

    const int lm = l & 15, lk = l >> 4;
    const float* ub = indiv_us + (size_t)b * (NAG * OBS);

    // H = relu(u @ W^T + b)
    #pragma unroll
    for (int mt = 0; mt < 2; mt++) {
        f16x8 af[3];
        #pragma unroll
        for (int ks = 0; ks < 3; ks++) {
            const float* up = ub + (mt * 16 + lm) * 96 + ks * 32 + lk * 8;
            float4 v0 = *(const float4*)up;
            float4 v1 = *(const float4*)(up + 4);
            af[ks] = (f16x8){ (f16)v0.x, (f16)v0.y, (f16)v0.z, (f16)v0.w,
                              (f16)v1.x, (f16)v1.y, (f16)v1.z, (f16)v1.w };
        }
        #pragma unroll
        for (int nt = 0; nt < 4; nt++) {
            f32x4 acc = {0.f, 0.f, 0.f, 0.f};
            #pragma unroll
            for (int ks = 0; ks < 3; ks++) {
                f16x8 bb = *(const f16x8*)&eWs[(nt * 16 + lm) * 104 + ks * 32 + lk * 8];
                acc = __builtin_amdgcn_mfma_f32_16x16x32_f16(af[ks], bb, acc, 0, 0, 0);
            }
            int col = nt * 16 + lm;
            float bias = edge_b[col];
            #pragma unroll
            for (int r = 0; r < 4; r++) {
                int row = mt * 16 + lk * 4 + r;
                float hv = acc[r] + bias;
                Hw[row * 66 + col] = (f16)(hv > 0.f ? hv : 0.f);
            }
        }
    }
    WSYNC();

    float bsum = 0.f;
    #pragma unroll
    for (int n = 0; n < 32; n++) bsum += (float)Hw[n * 66 + l];
    sbinv[l] = bsum > 0.f ? 1.f / bsum : 0.f;

    float dd = 0.f;
    #pragma unroll 8
    for (int e2 = 0; e2 < 32; e2++) {
        f16x2 h2 = *(const f16x2*)&Hw[nn * 66 + e2 * 2];
        dd += (float)h2.x * swa[half * 64 + e2 * 2] + (float)h2.y * swa[half * 64 + e2 * 2 + 1];
    }
    float dis = dd > 0.f ? rsqrtf(dd) : 0.f;
    sdis[l] = dis;
    if (half == 0) stt[nn] = dis * q;
    WSYNC();

    float s1 = 0.f;
    #pragma unroll
    for (int n = 0; n < 32; n++) s1 += (float)Hw[n * 66 + l] * stt[n];
    sv[l] = s1 * swa[l] * sbinv[l];
    WSYNC();

    float y1 = 0.f;
    #pragma unroll 8
    for (int e2 = 0; e2 < 32; e2++) {
        f16x2 h2 = *(const f16x2*)&Hw[nn * 66 + e2 * 2];
        y1 += (float)h2.x * sv[e2 * 2] + (float)h2.y * sv[e2 * 2 + 1];
    }
    float x2 = sdis[nn] * y1;
    if (half == 0) stt[nn] = sdis[32 + nn] * x2;
    WSYNC();

    float s2 = 0.f;
    #pragma unroll
    for (int n = 0; n < 32; n++) s2 += (float)Hw[n * 66 + l] * stt[n];
    sv[l] = s2 * swa[64 + l] * sbinv[l];
    WSYNC();

    float y2 = 0.f;
    #pragma unroll 8
    for (int e2 = 0; e2 < 32; e2++) {
        f16x2 h2 = *(const f16x2*)&Hw[nn * 66 + e2 * 2];
        y2 += (float)h2.x * sv[e2 * 2] + (float)h2.y * sv[e2 * 2 + 1];
    }

    // ---- fused mix epilogue (lanes 0-31 of each wave) ----
    float qsv = sdis[32 + nn] * y2;
    float w1v = fabsf(pa0 + bw1);
    float c1v = pc0 + bc1;
    float wwv = fabsf(pw0 + bww);
    float z = qsv * w1v + c1v;
    float qt = z > 0.f ? z : expm1f(z);
    float val = (half == 0) ? qt * wwv : 0.f;
    val += __shfl_xor(val, 1, 32);
    val += __shfl_xor(val, 2, 32);
    val += __shfl_xor(val, 4, 32);
    val += __shfl_xor(val, 8, 32);
    val += __shfl_xor(val, 16, 32);
    if (l == 0) out[b] = val + p96a + bhc;
}

// ======================= launch =======================
extern "C" void kernel_launch(void* const* d_in, const int* in_sizes, int n_in,
                              void* d_out, int out_size, void* d_ws, size_t ws_size,
                              hipStream_t stream) {
    const float* agent_qs = (const float*)d_in[0];
    const float* states   = (const float*)d_in[1];
    const float* indiv_us = (const float*)d_in[2];
    const float* edge_W   = (const float*)d_in[3];
    const float* edge_b   = (const float*)d_in[4];
    const float* wline1   = (const float*)d_in[5];
    const float* wline2   = (const float*)d_in[6];
    const float* hw1_w1 = (const float*)d_in[7];
    const float* hw1_b1 = (const float*)d_in[8];
    const float* hw1_w2 = (const float*)d_in[9];
    const float* hw1_b2 = (const float*)d_in[10];
    const float* hc1_w1 = (const float*)d_in[11];
    const float* hc1_b1 = (const float*)d_in[12];
    const float* hc1_w2 = (const float*)d_in[13];
    const float* hc1_b2 = (const float*)d_in[14];
    const float* hw_w1  = (const float*)d_in[15];
    const float* hw_b1  = (const float*)d_in[16];
    const float* hw_w2  = (const float*)d_in[17];
    const float* hw_b2  = (const float*)d_in[18];
    const float* hc_w1  = (const float*)d_in[19];
    const float* hc_b1  = (const float*)d_in[20];
    const float* hc_w2  = (const float*)d_in[21];
    const float* hc_b2  = (const float*)d_in[22];

    char* ws = (char*)d_ws;
    size_t o_states16 = 0;                                   // 33,554,432
    size_t o_W1t  = o_states16 + (size_t)BATCH * SDIM * 2;   // 2,097,152
    size_t o_b1   = o_W1t + (size_t)NH * SDIM * 2;           // 4096
    size_t o_W2t  = o_b1 + 4096;                             // 49,152
    size_t o_hcw2 = o_W2t + 49152;                           // 512
    size_t o_Pp   = o_hcw2 + 512;                            // 16384*104*4 = 6.8MB

    f16*   states16 = (f16*)(ws + o_states16);
    f16*   W1t      = (f16*)(ws + o_W1t);
    float* b1cat    = (float*)(ws + o_b1);
    f16*   W2t      = (f16*)(ws + o_W2t);
    f16*   hcw2     = (f16*)(ws + o_hcw2);
    float* Pp       = (float*)(ws + o_Pp);

    k_front<<<NB_FRONT, 256, 0, stream>>>(
        states,
        hw1_w1, hc1_w1, hw_w1, hc_w1, hw1_b1, hc1_b1, hw_b1, hc_b1,
        hw1_w2, hc1_w2, hw_w2, hc_w2,
        states16, W1t, b1cat, W2t, hcw2);
    k_gemm<<<256, 512, 0, stream>>>(states16, W1t, b1cat, W2t, hcw2, Pp);
    k_hgcn_ep<<<BATCH / 4, 256, 0, stream>>>(
        agent_qs, indiv_us, edge_W, edge_b, wline1, wline2, Pp,
        hw1_b2, hc1_b2, hw_b2, hc_b2, (float*)d_out);
}